// Round 8
// baseline (387.537 us; speedup 1.0000x reference)
//
#include <hip/hip_runtime.h>

#define NN 50000
#define NE 640000
#define NPAD 50176     // even; 196*256
#define SCAN_B 196     // ceil(NN/256)
#define OUT_CHUNKS 64
#define OUT_CE 10000   // 64*10000 = 640000
#define IN_CHUNKS 128
#define IN_CE 5000     // 128*5000 = 640000

typedef short bf16x8 __attribute__((ext_vector_type(8)));
typedef float f32x4 __attribute__((ext_vector_type(4)));

__device__ __forceinline__ unsigned short f2bf(float f) {
  unsigned int u = __float_as_uint(f);
  unsigned int r = (u + 0x7FFFu + ((u >> 16) & 1u)) >> 16;
  return (unsigned short)r;
}
__device__ __forceinline__ float bf2f(unsigned short h) {
  return __uint_as_float(((unsigned int)h) << 16);
}

// ---------------- LDS histogram: no global atomics ----------------
__global__ __launch_bounds__(256) void k_hist(const int* __restrict__ src,
                                              const int* __restrict__ dst,
                                              unsigned short* __restrict__ hist_out,
                                              unsigned short* __restrict__ hist_in) {
  __shared__ unsigned int h[NPAD / 2];
  int b = blockIdx.x, tid = threadIdx.x;
  for (int i = tid; i < NPAD / 2; i += 256) h[i] = 0;
  __syncthreads();
  if (b < OUT_CHUNKS) {
    int base = b * OUT_CE;
    for (int i = tid; i < OUT_CE; i += 256) {
      int n = src[base + i];
      atomicAdd(&h[n >> 1], (n & 1) ? 0x10000u : 1u);
    }
  } else {
    int base = (b - OUT_CHUNKS) * IN_CE;
    for (int i = tid; i < IN_CE; i += 256) {
      int n = dst[base + i];
      atomicAdd(&h[n >> 1], (n & 1) ? 0x10000u : 1u);
    }
  }
  __syncthreads();
  unsigned int* outp = (unsigned int*)((b < OUT_CHUNKS ? hist_out : hist_in) +
                                       (size_t)(b < OUT_CHUNKS ? b : b - OUT_CHUNKS) * NPAD);
  for (int i = tid; i < NPAD / 2; i += 256) outp[i] = h[i];
}

// ---------------- scan1: degree sums, norms, in-place chunk prefixes ----------------
__global__ __launch_bounds__(256) void k_scan1(const unsigned short* __restrict__ hist_out,
                                               unsigned short* __restrict__ hist_in,
                                               float* __restrict__ nsrc,
                                               float* __restrict__ ndst,
                                               int* __restrict__ in_cnt,
                                               int* __restrict__ bsum) {
  int t = threadIdx.x, n = blockIdx.x * 256 + t;
  int tot_in = 0;
  if (n < NN) {
    int od = 0;
#pragma unroll 8
    for (int c = 0; c < OUT_CHUNKS; ++c) od += hist_out[(size_t)c * NPAD + n];
    int pf = 0;
#pragma unroll 8
    for (int c = 0; c < IN_CHUNKS; ++c) {
      size_t idx = (size_t)c * NPAD + n;
      unsigned short v = hist_in[idx];
      hist_in[idx] = (unsigned short)pf;
      pf += v;
    }
    tot_in = pf;
    in_cnt[n] = tot_in;
    nsrc[n] = 1.0f / sqrtf((float)max(od, 1));
    ndst[n] = 1.0f / sqrtf((float)max(tot_in, 1));
  }
  int s = tot_in;
#pragma unroll
  for (int o = 32; o >= 1; o >>= 1) s += __shfl_down(s, o);
  __shared__ int ws4[4];
  if ((t & 63) == 0) ws4[t >> 6] = s;
  __syncthreads();
  if (t == 0) bsum[blockIdx.x] = ws4[0] + ws4[1] + ws4[2] + ws4[3];
}

// ---------------- scan3: row_start ----------------
__global__ __launch_bounds__(256) void k_scan3(const int* __restrict__ in_cnt,
                                               const int* __restrict__ bsum,
                                               int* __restrict__ row_start) {
  int b = blockIdx.x, t = threadIdx.x, lane = t & 63, w = t >> 6;
  __shared__ int wtot[4];
  __shared__ int sbase;
  {
    int v = (t < b) ? bsum[t] : 0;
#pragma unroll
    for (int o = 32; o >= 1; o >>= 1) v += __shfl_down(v, o);
    if (lane == 0) wtot[w] = v;
    __syncthreads();
    if (t == 0) sbase = wtot[0] + wtot[1] + wtot[2] + wtot[3];
    __syncthreads();
  }
  int i = b * 256 + t;
  int v = (i < NN) ? in_cnt[i] : 0;
  int sc = v;
#pragma unroll
  for (int o = 1; o < 64; o <<= 1) {
    int x = __shfl_up(sc, o);
    if (lane >= o) sc += x;
  }
  if (lane == 63) wtot[w] = sc;
  __syncthreads();
  int base = sbase;
  for (int j = 0; j < w; ++j) base += wtot[j];
  if (i < NN) row_start[i] = base + sc - v;
}

// ---------------- CSR fill: LDS re-histogram gives local rank, no atomics ----------------
__global__ __launch_bounds__(256) void k_fill(const int* __restrict__ src,
                                              const int* __restrict__ dst,
                                              const int* __restrict__ row_start,
                                              const unsigned short* __restrict__ prefix,
                                              int* __restrict__ col) {
  __shared__ unsigned int h[NPAD / 2];
  int c = blockIdx.x, tid = threadIdx.x;
  for (int i = tid; i < NPAD / 2; i += 256) h[i] = 0;
  __syncthreads();
  int base = c * IN_CE;
  for (int i = tid; i < IN_CE; i += 256) {
    int d = dst[base + i];
    unsigned int old = atomicAdd(&h[d >> 1], (d & 1) ? 0x10000u : 1u);
    int rank = (d & 1) ? (int)(old >> 16) : (int)(old & 0xFFFFu);
    col[row_start[d] + (int)prefix[(size_t)c * NPAD + d] + rank] = src[base + i];
  }
}

// ---------------- fused embed + weight prep ----------------
__global__ __launch_bounds__(256) void k_embed_prep(const float* __restrict__ nf,
                                                    const float* __restrict__ W,
                                                    const float* __restrict__ b,
                                                    const float* __restrict__ nsrc,
                                                    float* __restrict__ xs,
                                                    const float* __restrict__ Wg,
                                                    const float* __restrict__ Wo1,
                                                    unsigned short* __restrict__ wt) {
  int bid = blockIdx.x;
  if (bid < 25000) {
    int idx = bid * 256 + threadIdx.x;
    int n = idx >> 7, j = idx & 127;
    const float* f = nf + n * 4;
    float acc = b[j];
    acc += f[0] * W[j] + f[1] * W[128 + j] + f[2] * W[256 + j] + f[3] * W[384 + j];
    xs[idx] = acc * nsrc[n];
  } else {
    int idx = (bid - 25000) * 256 + threadIdx.x;  // 4 * 16384
    int mat = idx >> 14, rem = idx & 16383;
    int k = rem >> 7, n = rem & 127;
    const float* Wsrc = (mat < 3) ? (Wg + mat * 16384) : Wo1;
    float v = Wsrc[k * 128 + n];
    unsigned short hi = f2bf(v);
    float lo = v - bf2f(hi);
    unsigned short* basep = wt + mat * 32768;
    basep[n * 128 + k] = hi;
    basep[16384 + n * 128 + k] = f2bf(lo);
  }
}

// ---------------- fused layer: gather-SpMM -> LDS (swizzled bf16 hi/lo) -> MFMA GEMM ----------------
// mode 0: epilogue writes xs_out = relu(.)*nsrc (fp32) for the next layer
// mode 2: chains o1 GEMM (W2) in-LDS, then fused W_o2 dot -> outf[node]
__global__ __launch_bounds__(256) void k_layer(
    const float* __restrict__ xs, const int* __restrict__ col,
    const int* __restrict__ row_start, const int* __restrict__ in_cnt,
    const float* __restrict__ ndst, const float* __restrict__ nsrc,
    const unsigned short* __restrict__ Wth, const unsigned short* __restrict__ Wtl,
    const float* __restrict__ bias, float* __restrict__ outf,
    const unsigned short* __restrict__ W2h, const unsigned short* __restrict__ W2l,
    const float* __restrict__ bias2, const float* __restrict__ W_o2,
    const float* __restrict__ b_o2, int M, int mode) {
  __shared__ unsigned short sm[2 * 64 * 128];  // hi (16KB) then lo (16KB), XOR-swizzled rows
  __shared__ float smred[4][64];
  int tid = threadIdx.x;
  int lane = tid & 63, w = tid >> 6;
  int half = lane >> 5, ql = lane & 31;
  int tile0 = blockIdx.x * 64;

  // B fragments for GEMM1 (Wt layout [n][k] bf16)
  bf16x8 bh[2][4], bl[2][4];
  {
    int koff = (lane >> 4) * 8;
#pragma unroll
    for (int cf = 0; cf < 2; ++cf) {
      int n = w * 32 + cf * 16 + (lane & 15);
      const unsigned short* ph = Wth + (size_t)n * 128 + koff;
      const unsigned short* pl = Wtl + (size_t)n * 128 + koff;
#pragma unroll
      for (int kc = 0; kc < 4; ++kc) {
        bh[cf][kc] = *(const bf16x8*)(ph + kc * 32);
        bl[cf][kc] = *(const bf16x8*)(pl + kc * 32);
      }
    }
  }

  // Phase A: each wave gathers rows w, w+4, ..., w+60 (8-deep load ILP)
  const float4* X4 = (const float4*)xs;
  for (int it = 0; it < 16; ++it) {
    int row = it * 4 + w;
    int node = tile0 + row;
    float4 acc = make_float4(0.f, 0.f, 0.f, 0.f);
    int start = 0, cnt = 0;
    if (node < M) { start = row_start[node]; cnt = in_cnt[node]; }
    for (int base = 0; base < cnt; base += 64) {
      int m = min(cnt - base, 64);
      int ccol = (lane < m) ? col[start + base + lane] : 0;
      for (int jj = 0; jj < m; jj += 16) {
        int mm = m - 1;
        float4 v[8];
        float f[8];
#pragma unroll
        for (int u = 0; u < 8; ++u) {
          int idx = jj + u * 2 + half;
          int s = __shfl(ccol, min(idx, mm));
          f[u] = (idx < m) ? 1.f : 0.f;
          v[u] = X4[(size_t)s * 32 + ql];
        }
#pragma unroll
        for (int u = 0; u < 8; ++u) {
          acc.x = fmaf(f[u], v[u].x, acc.x);
          acc.y = fmaf(f[u], v[u].y, acc.y);
          acc.z = fmaf(f[u], v[u].z, acc.z);
          acc.w = fmaf(f[u], v[u].w, acc.w);
        }
      }
    }
    acc.x += __shfl_down(acc.x, 32);
    acc.y += __shfl_down(acc.y, 32);
    acc.z += __shfl_down(acc.z, 32);
    acc.w += __shfl_down(acc.w, 32);
    if (half == 0) {
      float nd = (node < M) ? ndst[node] : 0.f;
      float v0 = acc.x * nd, v1 = acc.y * nd, v2 = acc.z * nd, v3 = acc.w * nd;
      ushort4 h, l;
      h.x = f2bf(v0); l.x = f2bf(v0 - bf2f(h.x));
      h.y = f2bf(v1); l.y = f2bf(v1 - bf2f(h.y));
      h.z = f2bf(v2); l.z = f2bf(v2 - bf2f(h.z));
      h.w = f2bf(v3); l.w = f2bf(v3 - bf2f(h.w));
      // lane owns cols [4ql..4ql+3] -> chunk c = ql>>1, half (ql&1)
      int c = ql >> 1;
      int boff = row * 256 + ((c ^ (row & 7)) << 4) + (ql & 1) * 8;
      *(ushort4*)((char*)sm + boff) = h;
      *(ushort4*)((char*)sm + 16384 + boff) = l;
    }
  }
  __syncthreads();

  // GEMM1
  f32x4 acc[4][2] = {};
  int r15 = lane & 15, kq = lane >> 4;
  for (int kc = 0; kc < 4; ++kc) {
    bf16x8 ah[4], al[4];
#pragma unroll
    for (int m = 0; m < 4; ++m) {
      int row = m * 16 + r15;
      int boff = row * 256 + ((((kc * 4 + kq) ^ (row & 7))) << 4);
      ah[m] = *(const bf16x8*)((const char*)sm + boff);
      al[m] = *(const bf16x8*)((const char*)sm + 16384 + boff);
    }
#pragma unroll
    for (int m = 0; m < 4; ++m)
#pragma unroll
      for (int cf = 0; cf < 2; ++cf) {
        acc[m][cf] = __builtin_amdgcn_mfma_f32_16x16x32_bf16(ah[m], bh[cf][kc], acc[m][cf], 0, 0, 0);
        acc[m][cf] = __builtin_amdgcn_mfma_f32_16x16x32_bf16(ah[m], bl[cf][kc], acc[m][cf], 0, 0, 0);
        acc[m][cf] = __builtin_amdgcn_mfma_f32_16x16x32_bf16(al[m], bh[cf][kc], acc[m][cf], 0, 0, 0);
      }
  }

  if (mode == 0) {
    // D[row=(kq*4+i)+m*16][col=r15+cf*16+w*32] -> xs_out fp32 * nsrc
#pragma unroll
    for (int cf = 0; cf < 2; ++cf) {
      int colg = w * 32 + cf * 16 + r15;
      float bv = bias[colg];
#pragma unroll
      for (int m = 0; m < 4; ++m) {
#pragma unroll
        for (int i = 0; i < 4; ++i) {
          int gr = tile0 + m * 16 + kq * 4 + i;
          if (gr < M) {
            float v = fmaxf(acc[m][cf][i] + bv, 0.f);
            outf[(size_t)gr * 128 + colg] = v * nsrc[gr];
          }
        }
      }
    }
    return;
  }

  // mode 2: h3 = relu(acc+bias) -> LDS hi/lo (same swizzle), then o1 GEMM + W_o2 dot
  __syncthreads();  // all waves done reading sm before overwrite
#pragma unroll
  for (int cf = 0; cf < 2; ++cf) {
    int colg = w * 32 + cf * 16 + r15;
    float bv = bias[colg];
    int c2 = colg >> 3, cb = (colg & 7) * 2;
#pragma unroll
    for (int m = 0; m < 4; ++m) {
#pragma unroll
      for (int i = 0; i < 4; ++i) {
        int row = m * 16 + kq * 4 + i;
        float v = fmaxf(acc[m][cf][i] + bv, 0.f);
        unsigned short h = f2bf(v);
        int boff = row * 256 + ((c2 ^ (row & 7)) << 4) + cb;
        *(unsigned short*)((char*)sm + boff) = h;
        *(unsigned short*)((char*)sm + 16384 + boff) = f2bf(v - bf2f(h));
      }
    }
  }
  // o1 B fragments
  bf16x8 b2h[2][4], b2l[2][4];
  {
    int koff = (lane >> 4) * 8;
#pragma unroll
    for (int cf = 0; cf < 2; ++cf) {
      int n = w * 32 + cf * 16 + (lane & 15);
      const unsigned short* ph = W2h + (size_t)n * 128 + koff;
      const unsigned short* pl = W2l + (size_t)n * 128 + koff;
#pragma unroll
      for (int kc = 0; kc < 4; ++kc) {
        b2h[cf][kc] = *(const bf16x8*)(ph + kc * 32);
        b2l[cf][kc] = *(const bf16x8*)(pl + kc * 32);
      }
    }
  }
  f32x4 acc2[4][2] = {};
  __syncthreads();
  for (int kc = 0; kc < 4; ++kc) {
    bf16x8 ah[4], al[4];
#pragma unroll
    for (int m = 0; m < 4; ++m) {
      int row = m * 16 + r15;
      int boff = row * 256 + ((((kc * 4 + kq) ^ (row & 7))) << 4);
      ah[m] = *(const bf16x8*)((const char*)sm + boff);
      al[m] = *(const bf16x8*)((const char*)sm + 16384 + boff);
    }
#pragma unroll
    for (int m = 0; m < 4; ++m)
#pragma unroll
      for (int cf = 0; cf < 2; ++cf) {
        acc2[m][cf] = __builtin_amdgcn_mfma_f32_16x16x32_bf16(ah[m], b2h[cf][kc], acc2[m][cf], 0, 0, 0);
        acc2[m][cf] = __builtin_amdgcn_mfma_f32_16x16x32_bf16(ah[m], b2l[cf][kc], acc2[m][cf], 0, 0, 0);
        acc2[m][cf] = __builtin_amdgcn_mfma_f32_16x16x32_bf16(al[m], b2h[cf][kc], acc2[m][cf], 0, 0, 0);
      }
  }
  float w2v[2], bv2[2];
#pragma unroll
  for (int cf = 0; cf < 2; ++cf) {
    int colg = w * 32 + cf * 16 + r15;
    w2v[cf] = W_o2[colg];
    bv2[cf] = bias2[colg];
  }
#pragma unroll
  for (int m = 0; m < 4; ++m) {
#pragma unroll
    for (int i = 0; i < 4; ++i) {
      float p = fmaxf(acc2[m][0][i] + bv2[0], 0.f) * w2v[0] +
                fmaxf(acc2[m][1][i] + bv2[1], 0.f) * w2v[1];
#pragma unroll
      for (int msk = 1; msk < 16; msk <<= 1) p += __shfl_xor(p, msk);
      if (r15 == 0) smred[w][m * 16 + kq * 4 + i] = p;
    }
  }
  __syncthreads();
  if (tid < 64) {
    int gr = tile0 + tid;
    if (gr < M)
      outf[gr] = smred[0][tid] + smred[1][tid] + smred[2][tid] + smred[3][tid] + b_o2[0];
  }
}

extern "C" void kernel_launch(void* const* d_in, const int* in_sizes, int n_in,
                              void* d_out, int out_size, void* d_ws, size_t ws_size,
                              hipStream_t stream) {
  const float* node_feats = (const float*)d_in[0];
  const int* src = (const int*)d_in[1];
  const int* dst = (const int*)d_in[2];
  const float* W_emb = (const float*)d_in[3];
  const float* b_emb = (const float*)d_in[4];
  const float* W_g = (const float*)d_in[5];
  const float* b_g = (const float*)d_in[6];
  const float* W_o1 = (const float*)d_in[7];
  const float* b_o1 = (const float*)d_in[8];
  const float* W_o2 = (const float*)d_in[9];
  const float* b_o2 = (const float*)d_in[10];
  float* out = (float*)d_out;

  // Workspace layout (bytes). hist_* alias X_a (dead before embed writes X_a).
  // X_a/X_b ping-pong across layers (fused kernel reads one, writes the other).
  char* ws = (char*)d_ws;
  int* in_cnt    = (int*)(ws + 0);                        // 200,704
  int* row_start = (int*)(ws + 200704);                   // 200,704
  float* nsrc    = (float*)(ws + 401408);                 // 200,704
  float* ndst    = (float*)(ws + 602112);                 // 200,704
  int* bsum      = (int*)(ws + 802816);                   // 1,024
  int* col       = (int*)(ws + 803840);                   // 2,560,000
  unsigned short* wt = (unsigned short*)(ws + 3363840);   // 262,144
  float* Xa      = (float*)(ws + 3625984);                // 25,600,000
  unsigned short* hist_out = (unsigned short*)(ws + 3625984);            // 6,422,528 (in Xa)
  unsigned short* hist_in  = (unsigned short*)(ws + 3625984 + 6422528);  // 12,845,056 (in Xa)
  float* Xb      = (float*)(ws + 29225984);               // 25,600,000 -> ends 54,825,984

  k_hist<<<OUT_CHUNKS + IN_CHUNKS, 256, 0, stream>>>(src, dst, hist_out, hist_in);
  k_scan1<<<SCAN_B, 256, 0, stream>>>(hist_out, hist_in, nsrc, ndst, in_cnt, bsum);
  k_scan3<<<SCAN_B, 256, 0, stream>>>(in_cnt, bsum, row_start);
  k_fill<<<IN_CHUNKS, 256, 0, stream>>>(src, dst, row_start, hist_in, col);
  k_embed_prep<<<25256, 256, 0, stream>>>(node_feats, W_emb, b_emb, nsrc, Xa,
                                          W_g, W_o1, wt);

  int grid = (NN + 63) / 64;
  // layer 0: Xa -> Xb ; layer 1: Xb -> Xa ; layer 2(+o1+final): Xa -> out
  k_layer<<<grid, 256, 0, stream>>>(Xa, col, row_start, in_cnt, ndst, nsrc,
                                    wt + 0 * 32768, wt + 0 * 32768 + 16384,
                                    b_g + 0, Xb, nullptr, nullptr, nullptr,
                                    nullptr, nullptr, NN, 0);
  k_layer<<<grid, 256, 0, stream>>>(Xb, col, row_start, in_cnt, ndst, nsrc,
                                    wt + 1 * 32768, wt + 1 * 32768 + 16384,
                                    b_g + 128, Xa, nullptr, nullptr, nullptr,
                                    nullptr, nullptr, NN, 0);
  k_layer<<<grid, 256, 0, stream>>>(Xa, col, row_start, in_cnt, ndst, nsrc,
                                    wt + 2 * 32768, wt + 2 * 32768 + 16384,
                                    b_g + 256, out,
                                    wt + 3 * 32768, wt + 3 * 32768 + 16384,
                                    b_o1, W_o2, b_o2, NN, 2);
}